// Round 5
// baseline (1471.017 us; speedup 1.0000x reference)
//
#include <hip/hip_runtime.h>
#include <hip/hip_bf16.h>

#define N_NODES 16384
#define EDGE_CAP 128   // max expected degree ~97 (mean 65.5, sd 8.1; >7 sigma headroom)
#define ENC_BASE (N_NODES - N_NODES / 4)   // 12288: blocks >= this also run encoder

typedef float f32x4 __attribute__((ext_vector_type(4)));
typedef float f32x2 __attribute__((ext_vector_type(2)));

// ---------------------------------------------------------------------------
// Zero the per-row edge counters (ws arrives poisoned 0xAA). Must complete
// before any scan-kernel atomicAdd on cnts -> standalone ~2 us launch.
// ---------------------------------------------------------------------------
__global__ void zero_cnts_kernel(int* __restrict__ cnts)
{
    int i = blockIdx.x * 256 + threadIdx.x;
    if (i < N_NODES) cnts[i] = 0;
}

// ---------------------------------------------------------------------------
// MERGED upper-triangle adjacency scan + encoder.
// Scan: block i scans columns j > i (537 MB HBM stream, VALU mostly idle).
// Encoder: blocks 12288..16383 (the ones with the SHORTEST scan rows, and
// dispatched LAST — they arrive when the CUs are saturated with streaming
// from the heavy early blocks) also compute, for 4 rows each:
//   h1 = relu(x@w1+b1); h = relu(h1@w2+b2) -> global; hw = h@wg -> global.
// The encoder's pure-VALU work hides under the scan's memory stalls, making
// the previous 25-30 us encoder launch effectively free.
// ---------------------------------------------------------------------------
__global__ __launch_bounds__(256)
void scan_enc_kernel(const float* __restrict__ adj,
                     int* __restrict__ edges,
                     int* __restrict__ cnts,
                     const float* __restrict__ x,
                     const float* __restrict__ w1, const float* __restrict__ b1,
                     const float* __restrict__ w2, const float* __restrict__ b2,
                     const float* __restrict__ wg,
                     float* __restrict__ h, float* __restrict__ hw)
{
    __shared__ int   s_cnt;
    __shared__ int   s_base;
    __shared__ int   s_list[EDGE_CAP];
    __shared__ float s_x [4 * 32];
    __shared__ float s_h1[4 * 64];
    __shared__ float s_h [4 * 128];
    const int i   = blockIdx.x;
    const int tid = threadIdx.x;     // 0..255
    const int eb  = i - ENC_BASE;    // >= 0: this block also runs the encoder

    if (tid == 0) s_cnt = 0;
    if (eb >= 0 && tid < 128) s_x[tid] = x[(size_t)(eb * 4) * 32 + tid];
    __syncthreads();

    // ---------------- encoder (block-uniform branch) ----------------
    if (eb >= 0) {
        const int row0 = eb * 4;
        // h1 = relu(x @ w1 + b1): 4 rows x 64 outs = 256 -> 1 per thread
        {
            const int o  = tid & 63;
            const int rp = tid >> 6;
            float a = b1[o];
            #pragma unroll
            for (int k = 0; k < 32; ++k)
                a = fmaf(s_x[rp * 32 + k], w1[k * 64 + o], a);
            s_h1[rp * 64 + o] = fmaxf(a, 0.0f);
        }
        __syncthreads();
        // h = relu(h1 @ w2 + b2): 4 rows x 128 outs -> 2 per thread
        {
            const int o  = tid & 127;
            const int rp = (tid >> 7) * 2;
            float b = b2[o];
            float a0 = b, a1 = b;
            #pragma unroll 4
            for (int k = 0; k < 64; ++k) {
                float w = w2[k * 128 + o];
                a0 = fmaf(s_h1[rp * 64 + k],       w, a0);
                a1 = fmaf(s_h1[(rp + 1) * 64 + k], w, a1);
            }
            a0 = fmaxf(a0, 0.0f); a1 = fmaxf(a1, 0.0f);
            s_h[rp * 128 + o]       = a0;
            s_h[(rp + 1) * 128 + o] = a1;
            h[(size_t)(row0 + rp) * 128 + o]     = a0;
            h[(size_t)(row0 + rp + 1) * 128 + o] = a1;
        }
        __syncthreads();
        // hw = h @ wg (no bias, no relu)
        {
            const int o  = tid & 127;
            const int rp = (tid >> 7) * 2;
            float a0 = 0.0f, a1 = 0.0f;
            #pragma unroll 4
            for (int k = 0; k < 128; ++k) {
                float w = wg[k * 128 + o];
                a0 = fmaf(s_h[rp * 128 + k],       w, a0);
                a1 = fmaf(s_h[(rp + 1) * 128 + k], w, a1);
            }
            hw[(size_t)(row0 + rp) * 128 + o]     = a0;
            hw[(size_t)(row0 + rp + 1) * 128 + o] = a1;
        }
    }

    // ---------------- scan phase 1: LDS-only collection ----------------
    const f32x4* rp4 = reinterpret_cast<const f32x4*>(adj + (size_t)i * N_NODES);
    const int v0 = (i + 1) >> 2;     // first float4 that can contain j > i
    for (int vi = v0 + tid; vi < N_NODES / 4; vi += 256) {
        f32x4 v = __builtin_nontemporal_load(&rp4[vi]);
        if (v.x != 0.0f || v.y != 0.0f || v.z != 0.0f || v.w != 0.0f) {
            int base = vi * 4;
            #pragma unroll
            for (int q = 0; q < 4; ++q) {
                float val = (q == 0) ? v.x : (q == 1) ? v.y : (q == 2) ? v.z : v.w;
                int j = base + q;
                if (val != 0.0f && j > i) {
                    int p = atomicAdd(&s_cnt, 1);
                    if (p < EDGE_CAP) s_list[p] = j;
                }
            }
        }
    }
    __syncthreads();

    // ---------------- scan phase 2: bulk global inserts ----------------
    int c = s_cnt;
    if (c > EDGE_CAP) c = EDGE_CAP;                   // statistically impossible
    if (tid == 0) s_base = atomicAdd(&cnts[i], c);    // i-side: ONE reservation

    for (int k = tid; k < c; k += 256) {              // j-side: parallel atomics
        int j = s_list[k];
        int pj = atomicAdd(&cnts[j], 1);
        if (pj < EDGE_CAP) edges[(size_t)j * EDGE_CAP + pj] = i;
    }
    __syncthreads();                                  // s_base visible

    const int b = s_base;
    for (int k = tid; k < c; k += 256) {
        int pos = b + k;
        if (pos < EDGE_CAP) edges[(size_t)i * EDGE_CAP + pos] = s_list[k];
    }
}

// ---------------------------------------------------------------------------
// Fused SpMM + tail MLP: 4 rows per block, 256 threads.
// Phase 1 (spmm): one WAVE per row; lane owns 2 features. Gather is a
//   double-buffered software pipeline (edge list padded to x4 with d=0):
//   group g+1's 4 dwordx2 gathers are ISSUED before group g's FMAs wait on
//   them -> 8 loads in flight steady-state, LLC latency decoupled from FMAs.
// Phase 2 (tail): xd -> p1 -> p2 -> out, entirely in LDS.
// ---------------------------------------------------------------------------
__global__ __launch_bounds__(256)
void spmm_tail_kernel(const float* __restrict__ hw,
                      const int* __restrict__ edges,
                      const int* __restrict__ cnts,
                      const float* __restrict__ bg,
                      const float* __restrict__ h,
                      const float* __restrict__ wd,  const float* __restrict__ bd,
                      const float* __restrict__ wp1, const float* __restrict__ bp1,
                      const float* __restrict__ wp2, const float* __restrict__ bp2,
                      const float* __restrict__ wo,  const float* __restrict__ bo,
                      float* __restrict__ out)
{
    __shared__ int   s_e[4][EDGE_CAP];
    __shared__ float s_d[4][EDGE_CAP];
    __shared__ float s_a[4 * 128];   // xg, then p1
    __shared__ float s_h[4 * 128];   // h
    __shared__ float s_b[4 * 128];   // xd, then p2 (first 4*64)
    const int tid  = threadIdx.x;    // 0..255
    const int r    = tid >> 6;       // wave index == row within block
    const int lane = tid & 63;
    const int row0 = blockIdx.x * 4;
    const int row  = row0 + r;

    // stage h (independent of spmm): 512 floats / 256 threads
    s_h[tid]       = h[(size_t)row0 * 128 + tid];
    s_h[256 + tid] = h[(size_t)row0 * 128 + 256 + tid];

    // stage this wave's edge list + neighbor norms; pad to multiple of 4
    int c = cnts[row];
    if (c > EDGE_CAP) c = EDGE_CAP;
    for (int k = lane; k < c; k += 64) {
        int j = edges[(size_t)row * EDGE_CAP + k];
        s_e[r][k] = j;
        s_d[r][k] = rsqrtf((float)cnts[j] + 1.0f);
    }
    const int cg = (c + 3) & ~3;                 // cg <= 128
    for (int k = c + lane; k < cg; k += 64) {    // <=3 pad lanes
        s_e[r][k] = row;                         // harmless (d=0)
        s_d[r][k] = 0.0f;
    }
    __syncthreads();

    // spmm: lane owns features {2*lane, 2*lane+1}; double-buffered pipeline
    const f32x2* hw2 = reinterpret_cast<const f32x2*>(hw);
    const float di = rsqrtf((float)c + 1.0f);
    f32x2 v = hw2[(size_t)row * 64 + lane];      // self loop
    float ax0 = di * v.x, ay0 = di * v.y;
    float ax1 = 0.0f,     ay1 = 0.0f;

    const int ng = cg >> 2;
    float dA0, dA1, dA2, dA3;
    f32x2 uA0, uA1, uA2, uA3;
    if (ng > 0) {
        int jA0 = s_e[r][0], jA1 = s_e[r][1], jA2 = s_e[r][2], jA3 = s_e[r][3];
        dA0 = s_d[r][0]; dA1 = s_d[r][1]; dA2 = s_d[r][2]; dA3 = s_d[r][3];
        uA0 = hw2[(size_t)jA0 * 64 + lane];
        uA1 = hw2[(size_t)jA1 * 64 + lane];
        uA2 = hw2[(size_t)jA2 * 64 + lane];
        uA3 = hw2[(size_t)jA3 * 64 + lane];
    }
    for (int g = 0; g < ng; ++g) {
        const bool more = (g + 1 < ng);
        float dB0, dB1, dB2, dB3;
        f32x2 uB0, uB1, uB2, uB3;
        if (more) {                              // issue next group's loads
            const int nb = (g + 1) * 4;          // BEFORE waiting on group g
            int jB0 = s_e[r][nb], jB1 = s_e[r][nb + 1];
            int jB2 = s_e[r][nb + 2], jB3 = s_e[r][nb + 3];
            dB0 = s_d[r][nb];     dB1 = s_d[r][nb + 1];
            dB2 = s_d[r][nb + 2]; dB3 = s_d[r][nb + 3];
            uB0 = hw2[(size_t)jB0 * 64 + lane];
            uB1 = hw2[(size_t)jB1 * 64 + lane];
            uB2 = hw2[(size_t)jB2 * 64 + lane];
            uB3 = hw2[(size_t)jB3 * 64 + lane];
        }
        ax0 = fmaf(dA0, uA0.x, ax0);  ay0 = fmaf(dA0, uA0.y, ay0);
        ax1 = fmaf(dA1, uA1.x, ax1);  ay1 = fmaf(dA1, uA1.y, ay1);
        ax0 = fmaf(dA2, uA2.x, ax0);  ay0 = fmaf(dA2, uA2.y, ay0);
        ax1 = fmaf(dA3, uA3.x, ax1);  ay1 = fmaf(dA3, uA3.y, ay1);
        if (more) {
            dA0 = dB0; dA1 = dB1; dA2 = dB2; dA3 = dB3;
            uA0 = uB0; uA1 = uB1; uA2 = uB2; uA3 = uB3;
        }
    }
    {
        f32x2 bb = reinterpret_cast<const f32x2*>(bg)[lane];
        s_a[r * 128 + 2 * lane]     = fmaxf(fmaf(di, ax0 + ax1, bb.x), 0.0f);
        s_a[r * 128 + 2 * lane + 1] = fmaxf(fmaf(di, ay0 + ay1, bb.y), 0.0f);
    }
    __syncthreads();

    // xd = relu(xg @ wd + bd) -> s_b ; o=tid&127, rp: rows {0,1} or {2,3}
    {
        const int o  = tid & 127;
        const int rp = (tid >> 7) * 2;
        float b = bd[o];
        float a0 = b, a1 = b;
        #pragma unroll 4
        for (int kk = 0; kk < 128; ++kk) {
            float w = wd[(size_t)kk * 128 + o];
            a0 = fmaf(s_a[rp * 128 + kk],       w, a0);
            a1 = fmaf(s_a[(rp + 1) * 128 + kk], w, a1);
        }
        __syncthreads();             // all reads of s_a (xg) done
        s_b[rp * 128 + o]       = fmaxf(a0, 0.0f);
        s_b[(rp + 1) * 128 + o] = fmaxf(a1, 0.0f);
    }
    __syncthreads();

    // p1 = relu([xd, h] @ wp1 + bp1) -> s_a
    {
        const int o  = tid & 127;
        const int rp = (tid >> 7) * 2;
        float b = bp1[o];
        float a0 = b, a1 = b;
        #pragma unroll 4
        for (int kk = 0; kk < 128; ++kk) {
            float w = wp1[(size_t)kk * 128 + o];          // xd half
            a0 = fmaf(s_b[rp * 128 + kk],       w, a0);
            a1 = fmaf(s_b[(rp + 1) * 128 + kk], w, a1);
        }
        #pragma unroll 4
        for (int kk = 0; kk < 128; ++kk) {
            float w = wp1[(size_t)(128 + kk) * 128 + o];  // h half
            a0 = fmaf(s_h[rp * 128 + kk],       w, a0);
            a1 = fmaf(s_h[(rp + 1) * 128 + kk], w, a1);
        }
        s_a[rp * 128 + o]       = fmaxf(a0, 0.0f);
        s_a[(rp + 1) * 128 + o] = fmaxf(a1, 0.0f);
    }
    __syncthreads();

    // p2 = relu(p1 @ wp2 + bp2), O=64, 4 rows = 256 outputs, 1 per thread
    {
        const int o  = tid & 63;
        const int rr = tid >> 6;
        float a0 = bp2[o];
        #pragma unroll 4
        for (int kk = 0; kk < 128; ++kk)
            a0 = fmaf(s_a[rr * 128 + kk], wp2[(size_t)kk * 64 + o], a0);
        s_b[rr * 64 + o] = fmaxf(a0, 0.0f);
    }
    __syncthreads();

    // out = p2 @ wo + bo, O=5 (threads 0..19: rr=tid/5, a=tid%5)
    if (tid < 20) {
        const int rr = tid / 5, a = tid - rr * 5;
        float acc2 = bo[a];
        #pragma unroll 8
        for (int kk = 0; kk < 64; ++kk)
            acc2 = fmaf(s_b[rr * 64 + kk], wo[kk * 5 + a], acc2);
        out[(size_t)(row0 + rr) * 5 + a] = acc2;
    }
}

extern "C" void kernel_launch(void* const* d_in, const int* in_sizes, int n_in,
                              void* d_out, int out_size, void* d_ws, size_t ws_size,
                              hipStream_t stream)
{
    const float* x   = (const float*)d_in[0];
    const float* adj = (const float*)d_in[1];
    const float* w1  = (const float*)d_in[2];
    const float* b1  = (const float*)d_in[3];
    const float* w2  = (const float*)d_in[4];
    const float* b2  = (const float*)d_in[5];
    const float* wg  = (const float*)d_in[6];
    const float* bg  = (const float*)d_in[7];
    const float* wd  = (const float*)d_in[8];
    const float* bd  = (const float*)d_in[9];
    const float* wp1 = (const float*)d_in[10];
    const float* bp1 = (const float*)d_in[11];
    const float* wp2 = (const float*)d_in[12];
    const float* bp2 = (const float*)d_in[13];
    const float* wo  = (const float*)d_in[14];
    const float* bo  = (const float*)d_in[15];
    float* out = (float*)d_out;

    char* base = (char*)d_ws;
    // ws layout (~24.1 MB)
    float* h    = (float*)(base);                                  //  8 MB [N,128]
    float* hw   = (float*)(base + (8ull  << 20));                  //  8 MB [N,128]
    int*   cnts = (int*)  (base + (16ull << 20));                  // 64 KB
    int*   edges= (int*)  (base + (16ull << 20) + (64ull << 10));  //  8 MB [N,128]

    // Edge counters must be 0 before any scan atomics (ws arrives poisoned).
    zero_cnts_kernel<<<N_NODES / 256, 256, 0, stream>>>(cnts);

    // Merged scan+encoder: 537 MB nt-stream + encoder hidden under its stalls
    scan_enc_kernel<<<N_NODES, 256, 0, stream>>>(adj, edges, cnts,
                                                 x, w1, b1, w2, b2, wg, h, hw);

    // Fused GCN aggregation (pipelined gather) + tail MLP -> out
    spmm_tail_kernel<<<N_NODES / 4, 256, 0, stream>>>(hw, edges, cnts, bg, h,
                                                      wd, bd, wp1, bp1, wp2, bp2,
                                                      wo, bo, out);
}

// Round 6
// 1431.892 us; speedup vs baseline: 1.0273x; 1.0273x over previous
//
#include <hip/hip_runtime.h>
#include <hip/hip_bf16.h>

#define N_NODES 16384
#define EDGE_CAP 128   // max expected degree ~97 (mean 65.5, sd 8.1; >7 sigma headroom)

typedef float f32x4 __attribute__((ext_vector_type(4)));
typedef float f32x2 __attribute__((ext_vector_type(2)));

// ---------------------------------------------------------------------------
// Fused encoder: per 4-row block (128 threads), entirely in LDS:
//   h1 = relu(x@w1+b1)   [4,64]
//   h  = relu(h1@w2+b2)  [4,128]  -> global (tail needs it)
//   hw = h@wg            [4,128]  -> global (spmm needs it)
// Blocks 0..63 also zero the edge counters (ws arrives poisoned 0xAA).
// ---------------------------------------------------------------------------
__global__ void encoder_kernel(const float* __restrict__ x,
                               const float* __restrict__ w1, const float* __restrict__ b1,
                               const float* __restrict__ w2, const float* __restrict__ b2,
                               const float* __restrict__ wg,
                               float* __restrict__ h, float* __restrict__ hw,
                               int* __restrict__ cnts)
{
    __shared__ float s_x [4 * 32];
    __shared__ float s_h1[4 * 64];
    __shared__ float s_h [4 * 128];
    const int row0 = blockIdx.x * 4;
    const int tid = threadIdx.x;     // 0..127

    if (blockIdx.x < 64) {           // 64 blocks x 256 = 16384 counters
        cnts[blockIdx.x * 256 + tid]       = 0;
        cnts[blockIdx.x * 256 + 128 + tid] = 0;
    }

    // stage x: 4 rows x 32 = 128 contiguous floats
    s_x[tid] = x[(size_t)row0 * 32 + tid];
    __syncthreads();

    // h1 = relu(x @ w1 + b1): O=64. threads 0..63 -> rows 0,1; 64..127 -> rows 2,3
    {
        const int o  = tid & 63;
        const int rp = (tid >> 6) * 2;
        float b = b1[o];
        float a0 = b, a1 = b;
        #pragma unroll
        for (int k = 0; k < 32; ++k) {
            float w = w1[k * 64 + o];
            a0 = fmaf(s_x[rp * 32 + k],       w, a0);
            a1 = fmaf(s_x[(rp + 1) * 32 + k], w, a1);
        }
        s_h1[rp * 64 + o]       = fmaxf(a0, 0.0f);
        s_h1[(rp + 1) * 64 + o] = fmaxf(a1, 0.0f);
    }
    __syncthreads();

    // h = relu(h1 @ w2 + b2): O=128, all 128 threads, 4 rows
    {
        const int o = tid;
        float b = b2[o];
        float a0 = b, a1 = b, a2 = b, a3 = b;
        #pragma unroll 4
        for (int k = 0; k < 64; ++k) {
            float w = w2[k * 128 + o];
            a0 = fmaf(s_h1[k],        w, a0);
            a1 = fmaf(s_h1[64 + k],   w, a1);
            a2 = fmaf(s_h1[128 + k],  w, a2);
            a3 = fmaf(s_h1[192 + k],  w, a3);
        }
        a0 = fmaxf(a0, 0.0f); a1 = fmaxf(a1, 0.0f);
        a2 = fmaxf(a2, 0.0f); a3 = fmaxf(a3, 0.0f);
        s_h[o] = a0;  s_h[128 + o] = a1;  s_h[256 + o] = a2;  s_h[384 + o] = a3;
        h[(size_t)(row0 + 0) * 128 + o] = a0;
        h[(size_t)(row0 + 1) * 128 + o] = a1;
        h[(size_t)(row0 + 2) * 128 + o] = a2;
        h[(size_t)(row0 + 3) * 128 + o] = a3;
    }
    __syncthreads();

    // hw = h @ wg (no bias, no relu)
    {
        const int o = tid;
        float a0 = 0.0f, a1 = 0.0f, a2 = 0.0f, a3 = 0.0f;
        #pragma unroll 4
        for (int k = 0; k < 128; ++k) {
            float w = wg[k * 128 + o];
            a0 = fmaf(s_h[k],        w, a0);
            a1 = fmaf(s_h[128 + k],  w, a1);
            a2 = fmaf(s_h[256 + k],  w, a2);
            a3 = fmaf(s_h[384 + k],  w, a3);
        }
        hw[(size_t)(row0 + 0) * 128 + o] = a0;
        hw[(size_t)(row0 + 1) * 128 + o] = a1;
        hw[(size_t)(row0 + 2) * 128 + o] = a2;
        hw[(size_t)(row0 + 3) * 128 + o] = a3;
    }
}

// ---------------------------------------------------------------------------
// Upper-triangle adjacency scan, TWO-PHASE. Phase 1 touches only LDS
// (low-latency collect); phase 2 issues all j-side global atomics +
// scatters 128-wide in parallel so their latencies overlap across lanes.
// Non-temporal loads keep the read-once adj stream from evicting hw
// (needed by the spmm phase next) out of L2/LLC.
// ---------------------------------------------------------------------------
__global__ void tri_scan_kernel(const float* __restrict__ adj,
                                int* __restrict__ edges,
                                int* __restrict__ cnts)
{
    __shared__ int s_cnt;
    __shared__ int s_base;
    __shared__ int s_list[EDGE_CAP];
    const int i = blockIdx.x;
    const int tid = threadIdx.x;
    if (tid == 0) s_cnt = 0;
    __syncthreads();

    // ---- phase 1: scan, LDS-only collection ----
    const f32x4* rp = reinterpret_cast<const f32x4*>(adj + (size_t)i * N_NODES);
    const int v0 = (i + 1) >> 2;     // first float4 that can contain j > i
    for (int vi = v0 + tid; vi < N_NODES / 4; vi += 256) {
        f32x4 v = __builtin_nontemporal_load(&rp[vi]);
        if (v.x != 0.0f || v.y != 0.0f || v.z != 0.0f || v.w != 0.0f) {
            int base = vi * 4;
            #pragma unroll
            for (int q = 0; q < 4; ++q) {
                float val = (q == 0) ? v.x : (q == 1) ? v.y : (q == 2) ? v.z : v.w;
                int j = base + q;
                if (val != 0.0f && j > i) {
                    int p = atomicAdd(&s_cnt, 1);
                    if (p < EDGE_CAP) s_list[p] = j;
                }
            }
        }
    }
    __syncthreads();

    // ---- phase 2: bulk global inserts ----
    int c = s_cnt;
    if (c > EDGE_CAP) c = EDGE_CAP;                   // statistically impossible
    if (tid == 0) s_base = atomicAdd(&cnts[i], c);    // i-side: ONE reservation

    // j-side: c <= 128 parallel atomic+scatter, latencies overlap
    for (int k = tid; k < c; k += 256) {
        int j = s_list[k];
        int pj = atomicAdd(&cnts[j], 1);
        if (pj < EDGE_CAP) edges[(size_t)j * EDGE_CAP + pj] = i;
    }
    __syncthreads();                                  // s_base visible

    const int b = s_base;
    for (int k = tid; k < c; k += 256) {
        int pos = b + k;
        if (pos < EDGE_CAP) edges[(size_t)i * EDGE_CAP + pos] = s_list[k];
    }
}

// ---------------------------------------------------------------------------
// Fused SpMM + tail MLP: 4 rows per block, 256 threads.
// Phase 1 (spmm): one WAVE per row; lane owns 2 features. Gather loop is
//   manually 4x-unrolled (4 independent dwordx2 gathers in flight before
//   their FMAs) with split accumulators -> latency-pipelined, not serial.
// Phase 2 (tail): xd -> p1 -> p2 -> out, entirely in LDS.
// ---------------------------------------------------------------------------
__global__ void spmm_tail_kernel(const float* __restrict__ hw,
                                 const int* __restrict__ edges,
                                 const int* __restrict__ cnts,
                                 const float* __restrict__ bg,
                                 const float* __restrict__ h,
                                 const float* __restrict__ wd,  const float* __restrict__ bd,
                                 const float* __restrict__ wp1, const float* __restrict__ bp1,
                                 const float* __restrict__ wp2, const float* __restrict__ bp2,
                                 const float* __restrict__ wo,  const float* __restrict__ bo,
                                 float* __restrict__ out)
{
    __shared__ int   s_e[4][EDGE_CAP];
    __shared__ float s_d[4][EDGE_CAP];
    __shared__ float s_a[4 * 128];   // xg, then p1
    __shared__ float s_h[4 * 128];   // h
    __shared__ float s_b[4 * 128];   // xd, then p2 (first 4*64)
    const int tid  = threadIdx.x;    // 0..255
    const int r    = tid >> 6;       // wave index == row within block
    const int lane = tid & 63;
    const int row0 = blockIdx.x * 4;
    const int row  = row0 + r;

    // stage h (independent of spmm): 512 floats / 256 threads
    s_h[tid]       = h[(size_t)row0 * 128 + tid];
    s_h[256 + tid] = h[(size_t)row0 * 128 + 256 + tid];

    // stage this wave's edge list + neighbor norms
    int c = cnts[row];
    if (c > EDGE_CAP) c = EDGE_CAP;
    for (int k = lane; k < c; k += 64) {
        int j = edges[(size_t)row * EDGE_CAP + k];
        s_e[r][k] = j;
        s_d[r][k] = rsqrtf((float)cnts[j] + 1.0f);
    }
    __syncthreads();

    // spmm: lane owns features {2*lane, 2*lane+1}; 4x unrolled gather
    const f32x2* hw2 = reinterpret_cast<const f32x2*>(hw);
    const float di = rsqrtf((float)c + 1.0f);
    f32x2 v = hw2[(size_t)row * 64 + lane];     // self loop
    float ax0 = di * v.x, ay0 = di * v.y;
    float ax1 = 0.0f,     ay1 = 0.0f;
    int k = 0;
    for (; k + 4 <= c; k += 4) {
        int j0 = s_e[r][k], j1 = s_e[r][k + 1], j2 = s_e[r][k + 2], j3 = s_e[r][k + 3];
        f32x2 u0 = hw2[(size_t)j0 * 64 + lane];
        f32x2 u1 = hw2[(size_t)j1 * 64 + lane];
        f32x2 u2 = hw2[(size_t)j2 * 64 + lane];
        f32x2 u3 = hw2[(size_t)j3 * 64 + lane];
        float d0 = s_d[r][k], d1 = s_d[r][k + 1], d2 = s_d[r][k + 2], d3 = s_d[r][k + 3];
        ax0 = fmaf(d0, u0.x, ax0);  ay0 = fmaf(d0, u0.y, ay0);
        ax1 = fmaf(d1, u1.x, ax1);  ay1 = fmaf(d1, u1.y, ay1);
        ax0 = fmaf(d2, u2.x, ax0);  ay0 = fmaf(d2, u2.y, ay0);
        ax1 = fmaf(d3, u3.x, ax1);  ay1 = fmaf(d3, u3.y, ay1);
    }
    for (; k < c; ++k) {
        float d = s_d[r][k];
        f32x2 u = hw2[(size_t)s_e[r][k] * 64 + lane];
        ax0 = fmaf(d, u.x, ax0);  ay0 = fmaf(d, u.y, ay0);
    }
    {
        f32x2 bb = reinterpret_cast<const f32x2*>(bg)[lane];
        s_a[r * 128 + 2 * lane]     = fmaxf(fmaf(di, ax0 + ax1, bb.x), 0.0f);
        s_a[r * 128 + 2 * lane + 1] = fmaxf(fmaf(di, ay0 + ay1, bb.y), 0.0f);
    }
    __syncthreads();

    // xd = relu(xg @ wd + bd) -> s_b ; o=tid&127, rp: rows {0,1} or {2,3}
    {
        const int o  = tid & 127;
        const int rp = (tid >> 7) * 2;
        float b = bd[o];
        float a0 = b, a1 = b;
        #pragma unroll 4
        for (int kk = 0; kk < 128; ++kk) {
            float w = wd[(size_t)kk * 128 + o];
            a0 = fmaf(s_a[rp * 128 + kk],       w, a0);
            a1 = fmaf(s_a[(rp + 1) * 128 + kk], w, a1);
        }
        __syncthreads();             // all reads of s_a (xg) done
        s_b[rp * 128 + o]       = fmaxf(a0, 0.0f);
        s_b[(rp + 1) * 128 + o] = fmaxf(a1, 0.0f);
    }
    __syncthreads();

    // p1 = relu([xd, h] @ wp1 + bp1) -> s_a
    {
        const int o  = tid & 127;
        const int rp = (tid >> 7) * 2;
        float b = bp1[o];
        float a0 = b, a1 = b;
        #pragma unroll 4
        for (int kk = 0; kk < 128; ++kk) {
            float w = wp1[(size_t)kk * 128 + o];          // xd half
            a0 = fmaf(s_b[rp * 128 + kk],       w, a0);
            a1 = fmaf(s_b[(rp + 1) * 128 + kk], w, a1);
        }
        #pragma unroll 4
        for (int kk = 0; kk < 128; ++kk) {
            float w = wp1[(size_t)(128 + kk) * 128 + o];  // h half
            a0 = fmaf(s_h[rp * 128 + kk],       w, a0);
            a1 = fmaf(s_h[(rp + 1) * 128 + kk], w, a1);
        }
        s_a[rp * 128 + o]       = fmaxf(a0, 0.0f);
        s_a[(rp + 1) * 128 + o] = fmaxf(a1, 0.0f);
    }
    __syncthreads();

    // p2 = relu(p1 @ wp2 + bp2), O=64, 4 rows = 256 outputs, 1 per thread
    {
        const int o  = tid & 63;
        const int rr = tid >> 6;
        float a0 = bp2[o];
        #pragma unroll 4
        for (int kk = 0; kk < 128; ++kk)
            a0 = fmaf(s_a[rr * 128 + kk], wp2[(size_t)kk * 64 + o], a0);
        s_b[rr * 64 + o] = fmaxf(a0, 0.0f);
    }
    __syncthreads();

    // out = p2 @ wo + bo, O=5 (threads 0..19: rr=tid/5, a=tid%5)
    if (tid < 20) {
        const int rr = tid / 5, a = tid - rr * 5;
        float acc2 = bo[a];
        #pragma unroll 8
        for (int kk = 0; kk < 64; ++kk)
            acc2 = fmaf(s_b[rr * 64 + kk], wo[kk * 5 + a], acc2);
        out[(size_t)(row0 + rr) * 5 + a] = acc2;
    }
}

extern "C" void kernel_launch(void* const* d_in, const int* in_sizes, int n_in,
                              void* d_out, int out_size, void* d_ws, size_t ws_size,
                              hipStream_t stream)
{
    const float* x   = (const float*)d_in[0];
    const float* adj = (const float*)d_in[1];
    const float* w1  = (const float*)d_in[2];
    const float* b1  = (const float*)d_in[3];
    const float* w2  = (const float*)d_in[4];
    const float* b2  = (const float*)d_in[5];
    const float* wg  = (const float*)d_in[6];
    const float* bg  = (const float*)d_in[7];
    const float* wd  = (const float*)d_in[8];
    const float* bd  = (const float*)d_in[9];
    const float* wp1 = (const float*)d_in[10];
    const float* bp1 = (const float*)d_in[11];
    const float* wp2 = (const float*)d_in[12];
    const float* bp2 = (const float*)d_in[13];
    const float* wo  = (const float*)d_in[14];
    const float* bo  = (const float*)d_in[15];
    float* out = (float*)d_out;

    char* base = (char*)d_ws;
    // ws layout (~24.1 MB)
    float* h    = (float*)(base);                                  //  8 MB [N,128]
    float* hw   = (float*)(base + (8ull  << 20));                  //  8 MB [N,128]
    int*   cnts = (int*)  (base + (16ull << 20));                  // 64 KB
    int*   edges= (int*)  (base + (16ull << 20) + (64ull << 10));  //  8 MB [N,128]

    const int NB4 = N_NODES / 4;

    // Fused encoder (+ cnts zeroing): h = relu(relu(x@w1+b1)@w2+b2); hw = h@wg
    encoder_kernel<<<NB4, 128, 0, stream>>>(x, w1, b1, w2, b2, wg, h, hw, cnts);

    // Two-phase upper-triangle adjacency scan (537 MB HBM read, non-temporal)
    tri_scan_kernel<<<N_NODES, 256, 0, stream>>>(adj, edges, cnts);

    // Fused GCN aggregation (pipelined gather) + tail MLP -> out
    spmm_tail_kernel<<<NB4, 256, 0, stream>>>(hw, edges, cnts, bg, h,
                                              wd, bd, wp1, bp1, wp2, bp2,
                                              wo, bo, out);
}